// Round 1
// baseline (713.871 us; speedup 1.0000x reference)
//
#include <hip/hip_runtime.h>

// NLSPN deformable propagation, B=4, H=480, W=640, 18 steps.
// State g = f*conf; step: g' = A * sum_k aff_k * bilinear(g) + C.
// Offsets/affinities fixed across steps; recomputed per step in v1 (descriptor
// caching deferred until ws_size is confirmed; this variant needs ~29.5 MB ws).

#define HH 480
#define WW 640
#define BB 4
#define HWSZ (HH * WW)        // 307200
#define NPIX (BB * HWSZ)      // 1228800
#define PROP_T 18
#define SLACK 704             // > W+1 floats of slack each side of ping-pong bufs

struct f2u { float x, y; };   // natural align 4 -> legal unaligned-pair load

__device__ __forceinline__ float fast_tanh(float x) {
    x = fminf(fmaxf(x, -15.0f), 15.0f);
    float e = __expf(2.0f * x);
    return __fdividef(e - 1.0f, e + 1.0f);
}

__global__ __launch_bounds__(256) void precompute_kernel(
    const float* __restrict__ feat_init,
    const float* __restrict__ confidence,
    const float* __restrict__ feat_fix,
    float* __restrict__ g0,          // interior base (slack already applied)
    float2* __restrict__ ac_mid,
    float2* __restrict__ ac_last) {
    int p = blockIdx.x * 256 + threadIdx.x;
    if (p >= NPIX) return;
    float ff = feat_fix[p];
    float m  = (ff > 0.0f) ? 1.0f : 0.0f;
    float km = 1.0f - m;
    float conf = km * confidence[p] + m;
    float f0   = km * feat_init[p] + m * ff;
    g0[p] = f0 * conf;
    ac_mid[p]  = make_float2(conf * km, conf * m * ff);
    ac_last[p] = make_float2(km, m * ff);
}

__global__ __launch_bounds__(256) void step_kernel(
    const float* __restrict__ fin,    // interior base of input state (batch 0 px 0)
    float* __restrict__ fout,         // interior base of output (or d_out)
    const float* __restrict__ guid,
    const float* __restrict__ aff_scale,
    const float2* __restrict__ ac) {
    const int x = blockIdx.x * 64 + threadIdx.x;
    const int y = blockIdx.y * 4 + threadIdx.y;
    const int b = blockIdx.z;
    const int q = y * WW + x;
    const int pix = b * HWSZ + q;
    const float* gb = guid + (size_t)b * 24 * HWSZ + q;  // channel c at gb[c*HWSZ]

    // --- affinity normalization (fixed per pixel; recomputed each step in v1) ---
    const float inv_scale = __fdividef(1.0f, aff_scale[0] + 1e-8f);
    float t[8];
    float ssum = 1e-4f;
#pragma unroll
    for (int j = 0; j < 8; ++j) {
        float v = fast_tanh(gb[(16 + j) * HWSZ]) * inv_scale;
        t[j] = v;
        ssum += fabsf(v);
    }
    ssum = fmaxf(ssum, 1.0f);
    float rs = __fdividef(1.0f, ssum);
    float asum = 0.0f;
#pragma unroll
    for (int j = 0; j < 8; ++j) { t[j] *= rs; asum += t[j]; }
    const float aref = 1.0f - asum;

    const float* fb = fin + b * HWSZ;
    const float yf = (float)y, xf = (float)x;
    float acc = 0.0f;

    constexpr int KY[9] = {-1, -1, -1, 0, 0, 0, 1, 1, 1};
    constexpr int KX[9] = {-1, 0, 1, -1, 0, 1, -1, 0, 1};
#pragma unroll
    for (int k = 0; k < 9; ++k) {
        float dy, dx, ak;
        if (k == 4) {
            dy = 0.0f; dx = 0.0f; ak = aref;
        } else {
            const int n = (k < 4) ? k : (k - 1);
            dy = gb[(2 * n) * HWSZ];
            dx = gb[(2 * n + 1) * HWSZ];
            ak = t[n];
        }
        float py = yf + (float)KY[k] + dy;
        float px = xf + (float)KX[k] + dx;
        float y0f = floorf(py), x0f = floorf(px);
        float wy = py - y0f, wx = px - x0f;
        int y0 = (int)y0f, x0 = (int)x0f;
        // per-corner validity (zero weight if corner outside image)
        float vy0 = (y0 >= 0 && y0 < HH) ? 1.0f : 0.0f;
        float vy1 = (y0 >= -1 && y0 < HH - 1) ? 1.0f : 0.0f;
        float vx0 = (x0 >= 0 && x0 < WW) ? 1.0f : 0.0f;
        float vx1 = (x0 >= -1 && x0 < WW - 1) ? 1.0f : 0.0f;
        float omwy = 1.0f - wy, omwx = 1.0f - wx;
        float w00 = omwy * omwx * vy0 * vx0 * ak;
        float w01 = omwy * wx  * vy0 * vx1 * ak;
        float w10 = wy * omwx  * vy1 * vx0 * ak;
        float w11 = wy * wx    * vy1 * vx1 * ak;
        // clamped addressing; slack buffers make row -1 / row H reads safe
        int yc = min(max(y0, -1), HH - 1);
        int xc = min(max(x0, -1), WW - 1);
        int idx = yc * WW + xc;
        f2u r0 = *reinterpret_cast<const f2u*>(fb + idx);
        f2u r1 = *reinterpret_cast<const f2u*>(fb + idx + WW);
        acc += w00 * r0.x + w01 * r0.y + w10 * r1.x + w11 * r1.y;
    }

    float2 c2 = ac[pix];
    fout[pix] = c2.x * acc + c2.y;
}

extern "C" void kernel_launch(void* const* d_in, const int* in_sizes, int n_in,
                              void* d_out, int out_size, void* d_ws, size_t ws_size,
                              hipStream_t stream) {
    const float* feat_init  = (const float*)d_in[0];
    const float* guidance   = (const float*)d_in[1];
    const float* confidence = (const float*)d_in[2];
    const float* feat_fix   = (const float*)d_in[3];
    const float* aff_scale  = (const float*)d_in[4];

    // workspace layout: bufA | bufB | ac_mid | ac_last  (~29.5 MB)
    const size_t bufFloats = (size_t)NPIX + 2 * SLACK;
    float* bufA = (float*)d_ws;
    float* bufB = bufA + bufFloats;
    float2* acMid  = (float2*)(bufB + bufFloats);
    float2* acLast = acMid + NPIX;
    float* fA = bufA + SLACK;
    float* fB = bufB + SLACK;

    // zero slack (and everything) so weight-0 OOB gathers read finite zeros
    hipMemsetAsync(bufA, 0, bufFloats * sizeof(float), stream);
    hipMemsetAsync(bufB, 0, bufFloats * sizeof(float), stream);

    precompute_kernel<<<NPIX / 256, 256, 0, stream>>>(
        feat_init, confidence, feat_fix, fA, acMid, acLast);

    dim3 blk(64, 4, 1);
    dim3 grd(WW / 64, HH / 4, BB);
    for (int t = 0; t < PROP_T; ++t) {
        const float* fin = (t & 1) ? fB : fA;
        float* fout = (t == PROP_T - 1) ? (float*)d_out : ((t & 1) ? fA : fB);
        const float2* ac = (t == PROP_T - 1) ? acLast : acMid;
        step_kernel<<<grd, blk, 0, stream>>>(fin, fout, guidance, aff_scale, ac);
    }
}